// Round 3
// baseline (782.372 us; speedup 1.0000x reference)
//
#include <hip/hip_runtime.h>
#include <hip/hip_bf16.h>
#include <stdint.h>

// ---------------------------------------------------------------------------
// FusionNet: seq[t,d] = sum_r w[r]*(imu1[t]@A[r,:,d])*(vid1[t]@Bv[r,:,d]) + fb[d]
//            out[t]   = (relu(seq@W1 + b1) @ W2 + b2) / (anthro0*anthro1)
// R3: persistent grid=256 x 1024 threads (4 waves/SIMD). launch_bounds WITHOUT
// a min-waves arg: R2's (1024,4) forced a 64-VGPR budget -> scratch spills
// (WRITE_SIZE 453 MB). MLP W1-accum fused into d-loop to cut live registers.
// ---------------------------------------------------------------------------

#define NTOK   262144      // B*S = 64*4096
#define FDIM   128
#define RANKN  16
#define FUSED  10
#define KPAD   136         // 128 + 8 pad: 2-way-max LDS bank aliasing (free)
#define WTE    (FUSED*RANKN*KPAD)   // 21760 elements per bf16 weight table
#define TILES_PER_WAVE 4   // 256 blocks * 16 waves * 4 tiles * 16 tokens = NTOK

typedef unsigned short u16;
typedef __bf16 bf16x8 __attribute__((ext_vector_type(8)));
typedef float  f32x4  __attribute__((ext_vector_type(4)));

static __device__ __forceinline__ u16 f2bf(float f) {
    union { float f; uint32_t u; } c; c.f = f;
    uint32_t u = c.u + 0x7FFFu + ((c.u >> 16) & 1u);   // RNE
    return (u16)(u >> 16);
}

// ---------------------------------------------------------------------------
// Prep: transposed bf16 weight tables W[d][r][k] (k = feature-1), constant
// rows a0/b0 (the "ones" column), b1' = b1 + fusion_bias @ W1.
// fusion_weights[r] folded into imu side (weights and a0).
// ---------------------------------------------------------------------------
__global__ void prep_kernel(const float* __restrict__ imf, const float* __restrict__ vif,
                            const float* __restrict__ fw,  const float* __restrict__ fb,
                            const float* __restrict__ W1,  const float* __restrict__ b1,
                            u16* __restrict__ wImu, u16* __restrict__ wVid,
                            float* __restrict__ a0, float* __restrict__ b0,
                            float* __restrict__ b1p) {
    int idx = blockIdx.x * blockDim.x + threadIdx.x;
    if (idx < FUSED * RANKN * FDIM) {           // 20480
        int k = idx & 127;
        int r = (idx >> 7) & 15;
        int d = idx >> 11;
        int src = r * ((FDIM + 1) * FUSED) + (k + 1) * FUSED + d;  // factor[r,0,k+1,d]
        wImu[(d * RANKN + r) * KPAD + k] = f2bf(fw[r] * imf[src]);
        wVid[(d * RANKN + r) * KPAD + k] = f2bf(vif[src]);
    }
    if (idx < RANKN * FUSED) {                  // 160, layout [d][r]
        int r = idx & 15, d = idx >> 4;
        int src = r * ((FDIM + 1) * FUSED) + d; // factor[r,0,0,d]
        a0[idx] = fw[r] * imf[src];
        b0[idx] = vif[src];
    }
    if (idx < FDIM) {                           // fold fusion_bias through W1
        float acc = b1[idx];
        #pragma unroll
        for (int d = 0; d < FUSED; ++d) acc += fb[d] * W1[d * FDIM + idx];
        b1p[idx] = acc;
    }
}

// ---------------------------------------------------------------------------
// Main: persistent. 1024 threads = 16 waves (4 waves/SIMD), each wave owns
// TILES_PER_WAVE tiles of 16 tokens; no barrier inside the tile loop.
// NOTE: no min-waves arg — a forced 64-VGPR budget spills ~30 regs/thread
// to scratch (R2: +1.2 GB HBM traffic). Block residency caps VGPR at 128.
// ---------------------------------------------------------------------------
__launch_bounds__(1024)
__global__ void fusion_main(const float* __restrict__ imu, const float* __restrict__ vid,
                            const float* __restrict__ anthro,
                            const u16* __restrict__ wImuG, const u16* __restrict__ wVidG,
                            const float* __restrict__ a0g, const float* __restrict__ b0g,
                            const float* __restrict__ W1g, const float* __restrict__ b1pg,
                            const float* __restrict__ W2g, const float* __restrict__ b2g,
                            float* __restrict__ out) {
    extern __shared__ char smem[];
    u16*   sWimu = (u16*)smem;            // [10][16][136] bf16
    u16*   sWvid = sWimu + WTE;
    float* sA0   = (float*)(sWvid + WTE); // [10][16]
    float* sB0   = sA0 + 160;
    float* sW1   = sB0 + 160;             // [10][128] f32
    float* sB1   = sW1 + 1280;            // [128]
    float* sW2   = sB1 + 128;             // [128][2]

    // ---- stage weights to LDS once per (persistent) block ----
    {
        const uint4* srcI = (const uint4*)wImuG;
        const uint4* srcV = (const uint4*)wVidG;
        uint4* dstI = (uint4*)sWimu;
        uint4* dstV = (uint4*)sWvid;
        const int n16 = WTE * 2 / 16;     // 2720 per table
        for (int i = threadIdx.x; i < n16; i += blockDim.x) { dstI[i] = srcI[i]; dstV[i] = srcV[i]; }
        for (int i = threadIdx.x; i < 160;  i += blockDim.x) { sA0[i] = a0g[i]; sB0[i] = b0g[i]; }
        for (int i = threadIdx.x; i < 1280; i += blockDim.x) sW1[i] = W1g[i];
        for (int i = threadIdx.x; i < 128;  i += blockDim.x) sB1[i] = b1pg[i];
        for (int i = threadIdx.x; i < 256;  i += blockDim.x) sW2[i] = W2g[i];
    }
    __syncthreads();

    const int lane = threadIdx.x & 63;
    const int quad = lane >> 4;          // MFMA quad (k-group / row-group)
    const int r16  = lane & 15;          // token row (A) / rank col (B,C)
    const int wid  = threadIdx.x >> 6;   // 0..15
    const int gw   = blockIdx.x * 16 + wid;        // global wave id 0..4095
    const float b20 = b2g[0], b21 = b2g[1];

    #pragma unroll 1
    for (int tile = 0; tile < TILES_PER_WAVE; ++tile) {
        const int t0 = (gw * TILES_PER_WAVE + tile) * 16;

        // ---- A-fragments for 16 tokens, both modalities, 4 k-steps ----
        bf16x8 aI[4], aV[4];
        {
            const float* baseI = imu + (size_t)(t0 + r16) * FDIM + quad * 8;
            const float* baseV = vid + (size_t)(t0 + r16) * FDIM + quad * 8;
            #pragma unroll
            for (int kk = 0; kk < 4; ++kk) {
                f32x4 v0 = *(const f32x4*)(baseI + kk * 32);
                f32x4 v1 = *(const f32x4*)(baseI + kk * 32 + 4);
                f32x4 w0 = *(const f32x4*)(baseV + kk * 32);
                f32x4 w1 = *(const f32x4*)(baseV + kk * 32 + 4);
                bf16x8 a, b;
                #pragma unroll
                for (int j = 0; j < 4; ++j) {
                    a[j]     = (__bf16)v0[j];
                    a[j + 4] = (__bf16)v1[j];
                    b[j]     = (__bf16)w0[j];
                    b[j + 4] = (__bf16)w1[j];
                }
                aI[kk] = a;
                aV[kk] = b;
            }
        }

        // ---- per fused-dim d: U,V via MFMA, rank-butterfly, fused W1-accum ----
        // h[g][reg]: hidden pre-activation for column jc = r16+16g, token quad*4+reg
        float h[8][4];
        #pragma unroll
        for (int g = 0; g < 8; ++g) {
            float bb = sB1[r16 + 16 * g];
            #pragma unroll
            for (int reg = 0; reg < 4; ++reg) h[g][reg] = bb;
        }

        #pragma unroll
        for (int d = 0; d < FUSED; ++d) {
            f32x4 accU = {0.f, 0.f, 0.f, 0.f};
            f32x4 accV = {0.f, 0.f, 0.f, 0.f};
            const u16* bi = sWimu + (d * RANKN + r16) * KPAD + quad * 8;
            const u16* bv = sWvid + (d * RANKN + r16) * KPAD + quad * 8;
            #pragma unroll
            for (int kk = 0; kk < 4; ++kk) {
                bf16x8 bU = *(const bf16x8*)(const void*)(bi + kk * 32);
                accU = __builtin_amdgcn_mfma_f32_16x16x32_bf16(aI[kk], bU, accU, 0, 0, 0);
                bf16x8 bV = *(const bf16x8*)(const void*)(bv + kk * 32);
                accV = __builtin_amdgcn_mfma_f32_16x16x32_bf16(aV[kk], bV, accV, 0, 0, 0);
            }
            float a0v = sA0[d * RANKN + r16];
            float b0v = sB0[d * RANKN + r16];
            float p[4];
            #pragma unroll
            for (int reg = 0; reg < 4; ++reg) {
                float q = (accU[reg] + a0v) * (accV[reg] + b0v);
                q += __shfl_xor(q, 1, 16);
                q += __shfl_xor(q, 2, 16);
                q += __shfl_xor(q, 4, 16);
                q += __shfl_xor(q, 8, 16);
                p[reg] = q;              // seq[token, d] on all 16 lanes of quad
            }
            #pragma unroll
            for (int g = 0; g < 8; ++g) {
                float w1v = sW1[d * FDIM + r16 + 16 * g];
                #pragma unroll
                for (int reg = 0; reg < 4; ++reg) h[g][reg] += p[reg] * w1v;
            }
        }

        // ---- relu + W2 + 16-lane reduce ----
        float o0[4] = {0.f, 0.f, 0.f, 0.f};
        float o1[4] = {0.f, 0.f, 0.f, 0.f};
        #pragma unroll
        for (int g = 0; g < 8; ++g) {
            const int jc = r16 + 16 * g;
            float w20 = sW2[jc * 2], w21 = sW2[jc * 2 + 1];
            #pragma unroll
            for (int reg = 0; reg < 4; ++reg) {
                float hr = fmaxf(h[g][reg], 0.f);
                o0[reg] += hr * w20;
                o1[reg] += hr * w21;
            }
        }
        #pragma unroll
        for (int reg = 0; reg < 4; ++reg) {
            o0[reg] += __shfl_xor(o0[reg], 1, 16);
            o0[reg] += __shfl_xor(o0[reg], 2, 16);
            o0[reg] += __shfl_xor(o0[reg], 4, 16);
            o0[reg] += __shfl_xor(o0[reg], 8, 16);
            o1[reg] += __shfl_xor(o1[reg], 1, 16);
            o1[reg] += __shfl_xor(o1[reg], 2, 16);
            o1[reg] += __shfl_xor(o1[reg], 4, 16);
            o1[reg] += __shfl_xor(o1[reg], 8, 16);
        }

        // ---- epilogue: + b2, / (w*h), store float2 per token ----
        const int bidx = t0 >> 12;                         // S = 4096
        const float invwh = 1.0f / (anthro[2 * bidx] * anthro[2 * bidx + 1]);
        if (r16 == 0) {
            #pragma unroll
            for (int reg = 0; reg < 4; ++reg) {
                const int t = t0 + quad * 4 + reg;
                float2 o = make_float2((o0[reg] + b20) * invwh, (o1[reg] + b21) * invwh);
                *(float2*)(out + 2 * t) = o;
            }
        }
    }
}

// ---------------------------------------------------------------------------
extern "C" void kernel_launch(void* const* d_in, const int* in_sizes, int n_in,
                              void* d_out, int out_size, void* d_ws, size_t ws_size,
                              hipStream_t stream) {
    const float* imu    = (const float*)d_in[0];
    const float* vid    = (const float*)d_in[1];
    const float* anthro = (const float*)d_in[2];
    const float* imf    = (const float*)d_in[3];
    const float* vif    = (const float*)d_in[4];
    const float* fw     = (const float*)d_in[5];
    const float* fb     = (const float*)d_in[6];
    const float* W1     = (const float*)d_in[7];
    const float* b1     = (const float*)d_in[8];
    const float* W2     = (const float*)d_in[9];
    const float* b2     = (const float*)d_in[10];
    float* out = (float*)d_out;

    // workspace layout: [wImu bf16 21760][wVid bf16 21760][a0 160][b0 160][b1p 128]
    u16* wImu = (u16*)d_ws;
    u16* wVid = wImu + WTE;
    float* a0  = (float*)(wVid + WTE);
    float* b0  = a0 + 160;
    float* b1p = b0 + 160;

    prep_kernel<<<80, 256, 0, stream>>>(imf, vif, fw, fb, W1, b1, wImu, wVid, a0, b0, b1p);

    const size_t smem = (size_t)(2 * WTE) * sizeof(u16)
                      + (size_t)(160 + 160 + 1280 + 128 + 256) * sizeof(float); // 94976 B
    // persistent: 256 blocks x 16 waves x 4 tiles x 16 tokens = 262144
    fusion_main<<<256, 1024, smem, stream>>>(imu, vid, anthro, wImu, wVid,
                                             a0, b0, W1, b1p, W2, b2, out);
}

// Round 4
// 663.583 us; speedup vs baseline: 1.1790x; 1.1790x over previous
//
#include <hip/hip_runtime.h>
#include <hip/hip_bf16.h>
#include <stdint.h>

// ---------------------------------------------------------------------------
// FusionNet: seq[t,d] = sum_r w[r]*(imu1[t]@A[r,:,d])*(vid1[t]@Bv[r,:,d]) + fb[d]
//            out[t]   = (relu(seq@W1 + b1) @ W2 + b2) / (anthro0*anthro1)
// R4: 512-thread blocks (the ONLY config observed not to spill: R1 92 VGPR /
// 2 MB writes; 1024-thread blocks pin a 64-VGPR budget and spill 470 MB).
// Persistent grid=256 (weights staged once per CU), 8 tiles/wave with
// software-pipelined global prefetch (f32 in VGPRs) to hide HBM latency at
// 2 waves/SIMD. MLP cols re-owned as r16*8+g so W1/b1 reads are ds_read_b128.
// ---------------------------------------------------------------------------

#define NTOK   262144      // B*S = 64*4096
#define FDIM   128
#define RANKN  16
#define FUSED  10
#define KPAD   136         // 128 + 8 pad: 2-way-max LDS bank aliasing (free)
#define WTE    (FUSED*RANKN*KPAD)   // 21760 elements per bf16 weight table
#define TPW    8           // tiles per wave: 256 blk * 8 waves * 8 * 16 = NTOK

typedef unsigned short u16;
typedef __bf16 bf16x8 __attribute__((ext_vector_type(8)));
typedef float  f32x4  __attribute__((ext_vector_type(4)));
typedef float  f32x2  __attribute__((ext_vector_type(2)));

static __device__ __forceinline__ u16 f2bf(float f) {
    union { float f; uint32_t u; } c; c.f = f;
    uint32_t u = c.u + 0x7FFFu + ((c.u >> 16) & 1u);   // RNE
    return (u16)(u >> 16);
}

// ---------------------------------------------------------------------------
// Prep: transposed bf16 weight tables W[d][r][k] (k = feature-1), constant
// rows a0/b0 (the "ones" column), b1' = b1 + fusion_bias @ W1.
// fusion_weights[r] folded into imu side (weights and a0).
// ---------------------------------------------------------------------------
__global__ void prep_kernel(const float* __restrict__ imf, const float* __restrict__ vif,
                            const float* __restrict__ fw,  const float* __restrict__ fb,
                            const float* __restrict__ W1,  const float* __restrict__ b1,
                            u16* __restrict__ wImu, u16* __restrict__ wVid,
                            float* __restrict__ a0, float* __restrict__ b0,
                            float* __restrict__ b1p) {
    int idx = blockIdx.x * blockDim.x + threadIdx.x;
    if (idx < FUSED * RANKN * FDIM) {           // 20480
        int k = idx & 127;
        int r = (idx >> 7) & 15;
        int d = idx >> 11;
        int src = r * ((FDIM + 1) * FUSED) + (k + 1) * FUSED + d;  // factor[r,0,k+1,d]
        wImu[(d * RANKN + r) * KPAD + k] = f2bf(fw[r] * imf[src]);
        wVid[(d * RANKN + r) * KPAD + k] = f2bf(vif[src]);
    }
    if (idx < RANKN * FUSED) {                  // 160, layout [d][r]
        int r = idx & 15, d = idx >> 4;
        int src = r * ((FDIM + 1) * FUSED) + d; // factor[r,0,0,d]
        a0[idx] = fw[r] * imf[src];
        b0[idx] = vif[src];
    }
    if (idx < FDIM) {                           // fold fusion_bias through W1
        float acc = b1[idx];
        #pragma unroll
        for (int d = 0; d < FUSED; ++d) acc += fb[d] * W1[d * FDIM + idx];
        b1p[idx] = acc;
    }
}

// ---------------------------------------------------------------------------
// Main: persistent, 512 threads = 8 waves (2 waves/SIMD, 1 block/CU by LDS).
// Latency hidden by 1-tile-deep global prefetch held in VGPRs.
// ---------------------------------------------------------------------------
__launch_bounds__(512, 2)
__global__ void fusion_main(const float* __restrict__ imu, const float* __restrict__ vid,
                            const float* __restrict__ anthro,
                            const u16* __restrict__ wImuG, const u16* __restrict__ wVidG,
                            const float* __restrict__ a0g, const float* __restrict__ b0g,
                            const float* __restrict__ W1g, const float* __restrict__ b1pg,
                            const float* __restrict__ W2g, const float* __restrict__ b2g,
                            float* __restrict__ out) {
    extern __shared__ char smem[];
    u16*   sWimu = (u16*)smem;            // [10][16][136] bf16
    u16*   sWvid = sWimu + WTE;
    float* sA0   = (float*)(sWvid + WTE); // [10][16]
    float* sB0   = sA0 + 160;
    float* sW1   = sB0 + 160;             // [10][128] f32
    float* sB1   = sW1 + 1280;            // [128]
    float* sW2   = sB1 + 128;             // [128][2]

    // ---- stage weights to LDS once per (persistent) block ----
    {
        const uint4* srcI = (const uint4*)wImuG;
        const uint4* srcV = (const uint4*)wVidG;
        uint4* dstI = (uint4*)sWimu;
        uint4* dstV = (uint4*)sWvid;
        const int n16 = WTE * 2 / 16;     // 2720 per table
        for (int i = threadIdx.x; i < n16; i += blockDim.x) { dstI[i] = srcI[i]; dstV[i] = srcV[i]; }
        for (int i = threadIdx.x; i < 160;  i += blockDim.x) { sA0[i] = a0g[i]; sB0[i] = b0g[i]; }
        for (int i = threadIdx.x; i < 1280; i += blockDim.x) sW1[i] = W1g[i];
        for (int i = threadIdx.x; i < 128;  i += blockDim.x) sB1[i] = b1pg[i];
        for (int i = threadIdx.x; i < 256;  i += blockDim.x) sW2[i] = W2g[i];
    }
    __syncthreads();

    const int lane = threadIdx.x & 63;
    const int quad = lane >> 4;          // MFMA quad (k-group / row-group)
    const int r16  = lane & 15;          // token row (A) / rank col (B,C)
    const int wid  = threadIdx.x >> 6;   // 0..7
    const int gw   = blockIdx.x * 8 + wid;         // global wave id 0..2047
    const float b20 = b2g[0], b21 = b2g[1];

    // lane's global base: token gw*TPW*16 + r16, features quad*8..
    const float* baseI = imu + (size_t)(gw * TPW * 16 + r16) * FDIM + quad * 8;
    const float* baseV = vid + (size_t)(gw * TPW * 16 + r16) * FDIM + quad * 8;

    // ---- 1-tile-deep prefetch buffer (raw f32, 64 VGPRs) ----
    f32x4 P[16];
    auto issue = [&](int tile) {
        const float* bI = baseI + (size_t)tile * 16 * FDIM;
        const float* bV = baseV + (size_t)tile * 16 * FDIM;
        #pragma unroll
        for (int kk = 0; kk < 4; ++kk) {
            P[2 * kk]         = *(const f32x4*)(bI + kk * 32);
            P[2 * kk + 1]     = *(const f32x4*)(bI + kk * 32 + 4);
            P[8 + 2 * kk]     = *(const f32x4*)(bV + kk * 32);
            P[8 + 2 * kk + 1] = *(const f32x4*)(bV + kk * 32 + 4);
        }
    };
    issue(0);

    #pragma unroll 1
    for (int tile = 0; tile < TPW; ++tile) {
        // ---- convert prefetched f32 -> bf16 A-fragments ----
        bf16x8 aI[4], aV[4];
        #pragma unroll
        for (int kk = 0; kk < 4; ++kk) {
            f32x4 v0 = P[2 * kk], v1 = P[2 * kk + 1];
            f32x4 w0 = P[8 + 2 * kk], w1 = P[8 + 2 * kk + 1];
            bf16x8 a, b;
            #pragma unroll
            for (int j = 0; j < 4; ++j) {
                a[j]     = (__bf16)v0[j];
                a[j + 4] = (__bf16)v1[j];
                b[j]     = (__bf16)w0[j];
                b[j + 4] = (__bf16)w1[j];
            }
            aI[kk] = a;
            aV[kk] = b;
        }
        // P is free: issue next tile's loads so they overlap this compute
        if (tile + 1 < TPW) issue(tile + 1);

        // ---- hidden-layer accumulators; lane owns cols jc = r16*8+g ----
        float h[8][4];
        {
            f32x4 hb0 = *(const f32x4*)(sB1 + r16 * 8);
            f32x4 hb1 = *(const f32x4*)(sB1 + r16 * 8 + 4);
            #pragma unroll
            for (int g = 0; g < 4; ++g)
                #pragma unroll
                for (int reg = 0; reg < 4; ++reg) {
                    h[g][reg]     = hb0[g];
                    h[g + 4][reg] = hb1[g];
                }
        }

        // ---- per fused-dim d: MFMA pair, rank-butterfly, fused W1-accum ----
        #pragma unroll
        for (int d = 0; d < FUSED; ++d) {
            f32x4 accU = {0.f, 0.f, 0.f, 0.f};
            f32x4 accV = {0.f, 0.f, 0.f, 0.f};
            const u16* bi = sWimu + (d * RANKN + r16) * KPAD + quad * 8;
            const u16* bv = sWvid + (d * RANKN + r16) * KPAD + quad * 8;
            #pragma unroll
            for (int kk = 0; kk < 4; ++kk) {
                bf16x8 bU = *(const bf16x8*)(const void*)(bi + kk * 32);
                accU = __builtin_amdgcn_mfma_f32_16x16x32_bf16(aI[kk], bU, accU, 0, 0, 0);
                bf16x8 bV = *(const bf16x8*)(const void*)(bv + kk * 32);
                accV = __builtin_amdgcn_mfma_f32_16x16x32_bf16(aV[kk], bV, accV, 0, 0, 0);
            }
            float a0v = sA0[d * RANKN + r16];
            float b0v = sB0[d * RANKN + r16];
            f32x4 w1a = *(const f32x4*)(sW1 + d * FDIM + r16 * 8);
            f32x4 w1b = *(const f32x4*)(sW1 + d * FDIM + r16 * 8 + 4);
            float p[4];
            #pragma unroll
            for (int reg = 0; reg < 4; ++reg) {
                float q = (accU[reg] + a0v) * (accV[reg] + b0v);
                q += __shfl_xor(q, 1, 16);
                q += __shfl_xor(q, 2, 16);
                q += __shfl_xor(q, 4, 16);
                q += __shfl_xor(q, 8, 16);
                p[reg] = q;              // seq[token, d] on all 16 lanes of quad
            }
            #pragma unroll
            for (int g = 0; g < 4; ++g)
                #pragma unroll
                for (int reg = 0; reg < 4; ++reg) {
                    h[g][reg]     += p[reg] * w1a[g];
                    h[g + 4][reg] += p[reg] * w1b[g];
                }
        }

        // ---- relu + W2 + 16-lane reduce ----
        float o0[4] = {0.f, 0.f, 0.f, 0.f};
        float o1[4] = {0.f, 0.f, 0.f, 0.f};
        #pragma unroll
        for (int g = 0; g < 8; ++g) {
            f32x2 w2 = *(const f32x2*)(sW2 + (r16 * 8 + g) * 2);
            #pragma unroll
            for (int reg = 0; reg < 4; ++reg) {
                float hr = fmaxf(h[g][reg], 0.f);
                o0[reg] += hr * w2[0];
                o1[reg] += hr * w2[1];
            }
        }
        #pragma unroll
        for (int reg = 0; reg < 4; ++reg) {
            o0[reg] += __shfl_xor(o0[reg], 1, 16);
            o0[reg] += __shfl_xor(o0[reg], 2, 16);
            o0[reg] += __shfl_xor(o0[reg], 4, 16);
            o0[reg] += __shfl_xor(o0[reg], 8, 16);
            o1[reg] += __shfl_xor(o1[reg], 1, 16);
            o1[reg] += __shfl_xor(o1[reg], 2, 16);
            o1[reg] += __shfl_xor(o1[reg], 4, 16);
            o1[reg] += __shfl_xor(o1[reg], 8, 16);
        }

        // ---- epilogue: + b2, / (w*h), store float2 per token ----
        const int t0 = (gw * TPW + tile) * 16;
        const int bidx = t0 >> 12;                         // S = 4096
        const float invwh = 1.0f / (anthro[2 * bidx] * anthro[2 * bidx + 1]);
        if (r16 == 0) {
            #pragma unroll
            for (int reg = 0; reg < 4; ++reg) {
                const int t = t0 + quad * 4 + reg;
                float2 o = make_float2((o0[reg] + b20) * invwh, (o1[reg] + b21) * invwh);
                *(float2*)(out + 2 * t) = o;
            }
        }
    }
}

// ---------------------------------------------------------------------------
extern "C" void kernel_launch(void* const* d_in, const int* in_sizes, int n_in,
                              void* d_out, int out_size, void* d_ws, size_t ws_size,
                              hipStream_t stream) {
    const float* imu    = (const float*)d_in[0];
    const float* vid    = (const float*)d_in[1];
    const float* anthro = (const float*)d_in[2];
    const float* imf    = (const float*)d_in[3];
    const float* vif    = (const float*)d_in[4];
    const float* fw     = (const float*)d_in[5];
    const float* fb     = (const float*)d_in[6];
    const float* W1     = (const float*)d_in[7];
    const float* b1     = (const float*)d_in[8];
    const float* W2     = (const float*)d_in[9];
    const float* b2     = (const float*)d_in[10];
    float* out = (float*)d_out;

    // workspace layout: [wImu bf16 21760][wVid bf16 21760][a0 160][b0 160][b1p 128]
    u16* wImu = (u16*)d_ws;
    u16* wVid = wImu + WTE;
    float* a0  = (float*)(wVid + WTE);
    float* b0  = a0 + 160;
    float* b1p = b0 + 160;

    prep_kernel<<<80, 256, 0, stream>>>(imf, vif, fw, fb, W1, b1, wImu, wVid, a0, b0, b1p);

    const size_t smem = (size_t)(2 * WTE) * sizeof(u16)
                      + (size_t)(160 + 160 + 1280 + 128 + 256) * sizeof(float); // 94976 B
    // persistent: 256 blocks x 8 waves x 8 tiles x 16 tokens = 262144
    fusion_main<<<256, 512, smem, stream>>>(imu, vid, anthro, wImu, wVid,
                                            a0, b0, W1, b1p, W2, b2, out);
}